// Round 10
// baseline (1735.916 us; speedup 1.0000x reference)
//
#include <hip/hip_runtime.h>

#define T_LEN 2048
#define HID   256
#define G4    1024
#define EMBD  128
#define VOCAB 128
#define OUTC  2
#define BSUB  2           // batch rows per chain
#define NWG   64
#define CHK   64          // x chunk staged in LDS
#define XCHS  72          // xch row stride (ints)
#define HSB   288         // habuf row stride bytes
#define LOG2E 1.44269504088896340736f

typedef int   i32x4 __attribute__((ext_vector_type(4)));
typedef float f32x4 __attribute__((ext_vector_type(4)));

// Device-global scratch rebuilt every launch (kernel-boundary coherence, no fences).
// Pbuf swizzled: [v][w][nt][l15][g] -- each lane's 4 xg values are 16 contiguous bytes.
__device__ __align__(16) float Pbuf[VOCAB * G4];
__device__ __align__(16) signed char Wqb[G4 * HID];   // int8 W_hh, row-major [gatecol][k]
__device__ float Winv[G4];                            // m/(127^2) * per-gate exp2 scale

__global__ void build_P(const float* __restrict__ emb, const float* __restrict__ W_ih,
                        const float* __restrict__ b_ih, const float* __restrict__ b_hh) {
    const int v = blockIdx.x >> 2;
    const int c = ((blockIdx.x & 3) << 8) + threadIdx.x;   // gate-col 0..1023
    __shared__ float es[EMBD];
    if (threadIdx.x < EMBD) es[threadIdx.x] = emb[v * EMBD + threadIdx.x];
    __syncthreads();
    const float* wr = W_ih + c * EMBD;
    float acc = 0.f;
    #pragma unroll 8
    for (int e = 0; e < EMBD; ++e) acc += es[e] * wr[e];
    const float ks = ((c >> 8) == 2) ? (-2.f * LOG2E) : (-LOG2E);
    // c = g*256 + w*32 + nt*16 + l15  ->  idx = v*1024 + w*128 + nt*64 + l15*4 + g
    const int g  = c >> 8;
    const int rr = c & 255;
    const int wi = rr >> 5;
    const int nt = (rr >> 4) & 1;
    const int l  = rr & 15;
    Pbuf[v * G4 + wi * 128 + nt * 64 + l * 4 + g] = (acc + b_ih[c] + b_hh[c]) * ks;
}

// per-row symmetric int8 quantization of W_hh (1024 rows x 256)
__global__ void quant_W(const float* __restrict__ W_hh) {
    const int row = blockIdx.x;
    const int k   = threadIdx.x;
    __shared__ float red[4];
    const float wv = W_hh[row * HID + k];
    float a = fabsf(wv);
    #pragma unroll
    for (int o = 32; o > 0; o >>= 1) a = fmaxf(a, __shfl_down(a, o, 64));
    if ((k & 63) == 0) red[k >> 6] = a;
    __syncthreads();
    const float m = fmaxf(fmaxf(fmaxf(red[0], red[1]), red[2]), fmaxf(red[3], 1e-30f));
    Wqb[row * HID + k] = (signed char)(int)rintf(wv * (127.f / m));
    const float ks = ((row >> 8) == 2) ? (-2.f * LOG2E) : (-LOG2E);
    if (k == 0) Winv[row] = m * (1.f / (127.f * 127.f)) * ks;
}

// r = 1/(1+2^p).  p = -x*log2e -> sigmoid(x); tanh(x) = 2*r(-2x*log2e)-1.
__device__ __forceinline__ float sig_p(float p) {
    return __builtin_amdgcn_rcpf(1.f + __builtin_amdgcn_exp2f(p));
}

// 64 WGs x 512 thr: one WG = one chain of 2 batch rows. Gate math split into two
// exec-masked passes: ntq=0 lanes fire right after the a0 MFMA chain (hides under
// the a1 chain's pipe drain); ntq=1 lanes after a1. Only the last wave's second
// pass remains exposed beyond the matrix-pipe floor.
__global__ __launch_bounds__(512, 2) void lstm_chain(
        const int* __restrict__ x, const float* __restrict__ fc_W,
        const float* __restrict__ fc_b, float* __restrict__ out) {
    __shared__ __align__(16) signed char habuf[2][BSUB * HSB];
    __shared__ int   xch[BSUB * XCHS];
    __shared__ float hfin[BSUB * HID];

    const int tid  = threadIdx.x;
    const int w    = tid >> 6;       // wave 0..7: owns units [32w, 32w+32), all 4 gates
    const int lane = tid & 63;
    const int l15  = lane & 15;
    const int quad = lane >> 4;
    const int bbase = blockIdx.x * BSUB;
    const int ub    = w * 32;
    const int bq    = quad >> 1;              // this lane's batch row
    const int ntq   = quad & 1;               // this lane's acc tile
    const int colq  = ub + ntq * 16 + l15;    // this lane's gate-col (within gate block)

    // persistent int8 B fragments: 2 tiles x 4 gates x 4 K-chunks x 4 regs = 128 regs
    i32x4 Bf[2][4][4];
    #pragma unroll
    for (int nt = 0; nt < 2; ++nt)
        #pragma unroll
        for (int g = 0; g < 4; ++g) {
            const signed char* wr = Wqb + (size_t)(g * HID + ub + nt * 16 + l15) * HID;
            #pragma unroll
            for (int kt = 0; kt < 4; ++kt)
                Bf[nt][g][kt] = *(const i32x4*)(wr + kt * 64 + quad * 16);
        }
    float winvv[4];                           // per-gate dequant for THIS lane's col
    #pragma unroll
    for (int g = 0; g < 4; ++g) winvv[g] = Winv[g * HID + colq];

    if (tid < BSUB * HSB / 4) ((int*)habuf[0])[tid] = 0;   // h_0 = 0

    float cst = 0.f;                          // single cell state per lane
    f32x4 xga, xgb;                           // double-buffered xg (4 gates)
    const i32x4 zero4 = {0, 0, 0, 0};
    const float* pbase = Pbuf + w * 128 + ntq * 64 + l15 * 4;
    const signed char* habA = habuf[0] + (l15 >> 3) * HSB + quad * 16;
    const signed char* habB = habuf[1] + (l15 >> 3) * HSB + quad * 16;

#define GATHER(TT, XG)                                                        \
    {                                                                         \
        const int xv = xch[bq * XCHS + (TT)];                                 \
        XG = *(const f32x4*)(pbase + (size_t)xv * G4);                        \
    }

// gate math for this lane's single cell, reading acc tile ACC (element 0)
#define GATE_BODY(ACC, XC, HN, TCUR)                                          \
    {                                                                         \
        const float is = sig_p(fmaf((float)ACC[0][0], winvv[0], XC[0]));      \
        const float fs = sig_p(fmaf((float)ACC[1][0], winvv[1], XC[1]));      \
        const float gt = fmaf(2.f, sig_p(fmaf((float)ACC[2][0], winvv[2], XC[2])), -1.f); \
        const float os = sig_p(fmaf((float)ACC[3][0], winvv[3], XC[3]));      \
        const float c  = fmaf(fs, cst, is * gt);                              \
        cst = c;                                                              \
        const float hq = fmaf(254.f, sig_p(c * (-2.f * LOG2E)), -127.f) * os; \
        (HN)[bq * HSB + colq] = (signed char)(int)rintf(hq);                  \
        if ((TCUR) == T_LEN - 1) hfin[bq * HID + colq] = hq * (1.f / 127.f);  \
    }

#define STEP(HAB, HN, XC, XN, PF, TT, TCUR)                                   \
    {                                                                         \
        i32x4 af[4];                                                          \
        _Pragma("unroll")                                                     \
        for (int kt = 0; kt < 4; ++kt)                                        \
            af[kt] = *(const i32x4*)((HAB) + kt * 64);                        \
        if (PF) GATHER((TT), XN);                                             \
        i32x4 a0[4], a1[4];                                                   \
        _Pragma("unroll")                                                     \
        for (int g = 0; g < 4; ++g)                                           \
            a0[g] = __builtin_amdgcn_mfma_i32_16x16x64_i8(af[0], Bf[0][g][0], zero4, 0, 0, 0); \
        _Pragma("unroll")                                                     \
        for (int kt = 1; kt < 4; ++kt)                                        \
            _Pragma("unroll")                                                 \
            for (int g = 0; g < 4; ++g)                                       \
                a0[g] = __builtin_amdgcn_mfma_i32_16x16x64_i8(af[kt], Bf[0][g][kt], a0[g], 0, 0, 0); \
        _Pragma("unroll")                                                     \
        for (int g = 0; g < 4; ++g)                                           \
            a1[g] = __builtin_amdgcn_mfma_i32_16x16x64_i8(af[0], Bf[1][g][0], zero4, 0, 0, 0); \
        _Pragma("unroll")                                                     \
        for (int kt = 1; kt < 4; ++kt)                                        \
            _Pragma("unroll")                                                 \
            for (int g = 0; g < 4; ++g)                                       \
                a1[g] = __builtin_amdgcn_mfma_i32_16x16x64_i8(af[kt], Bf[1][g][kt], a1[g], 0, 0, 0); \
        /* pass 1: ntq=0 lanes need only the a0 chain -> runs inside a1's drain */ \
        if (ntq == 0) GATE_BODY(a0, XC, HN, TCUR);                            \
        /* pass 2: ntq=1 lanes after a1 completes */                          \
        if (ntq != 0) GATE_BODY(a1, XC, HN, TCUR);                            \
        __syncthreads();                                                      \
    }

    #pragma unroll 1
    for (int ch = 0; ch < T_LEN / CHK; ++ch) {
        // refill x chunk (prev step's end-barrier protects old readers)
        if (tid < BSUB * CHK)
            xch[(tid >> 6) * XCHS + (tid & 63)] =
                x[(bbase + (tid >> 6)) * T_LEN + ch * CHK + (tid & 63)];
        __syncthreads();
        GATHER(0, xga);
        const int tb = ch * CHK;
        #pragma unroll 1
        for (int tt = 0; tt < CHK; tt += 2) {
            STEP(habA, habuf[1], xga, xgb, 1, tt + 1, tb + tt);
            STEP(habB, habuf[0], xgb, xga, (tt < CHK - 2), tt + 2, tb + tt + 1);
        }
    }
#undef STEP
#undef GATE_BODY
#undef GATHER

    // FC epilogue: logits[b,o] = hT[b,:] . fc_W[o,:] + fc_b[o]
    if (tid < BSUB * OUTC) {
        const int b = tid >> 1, o = tid & 1;
        float s = fc_b[o];
        #pragma unroll 8
        for (int j = 0; j < HID; ++j) s += hfin[b * HID + j] * fc_W[o * HID + j];
        out[(bbase + b) * OUTC + o] = s;
    }
}

extern "C" void kernel_launch(void* const* d_in, const int* in_sizes, int n_in,
                              void* d_out, int out_size, void* d_ws, size_t ws_size,
                              hipStream_t stream) {
    const int*   x    = (const int*)  d_in[0];
    const float* emb  = (const float*)d_in[1];
    const float* W_ih = (const float*)d_in[2];
    const float* W_hh = (const float*)d_in[3];
    const float* b_ih = (const float*)d_in[4];
    const float* b_hh = (const float*)d_in[5];
    const float* fc_W = (const float*)d_in[6];
    const float* fc_b = (const float*)d_in[7];
    float* out = (float*)d_out;
    (void)d_ws; (void)ws_size;

    build_P<<<dim3(VOCAB * 4), dim3(256), 0, stream>>>(emb, W_ih, b_ih, b_hh);
    quant_W<<<dim3(G4), dim3(HID), 0, stream>>>(W_hh);
    lstm_chain<<<dim3(NWG), dim3(512), 0, stream>>>(x, fc_W, fc_b, out);
}

// Round 11
// 1410.710 us; speedup vs baseline: 1.2305x; 1.2305x over previous
//
#include <hip/hip_runtime.h>

#define T_LEN 2048
#define HID   256
#define G4    1024
#define EMBD  128
#define VOCAB 128
#define OUTC  2
#define BSUB  2           // batch rows per chain
#define NWG   64
#define CHK   64          // x chunk staged in LDS
#define XCHS  72          // xch row stride (ints)
#define HSB   288         // habuf row stride bytes
#define LOG2E 1.44269504088896340736f

typedef int   i32x4 __attribute__((ext_vector_type(4)));
typedef float f32x4 __attribute__((ext_vector_type(4)));

// Device-global scratch rebuilt every launch (kernel-boundary coherence, no fences).
// Pbuf swizzled: [v][w][nt][l15][g] -- each lane's 4 xg values are 16 contiguous bytes.
__device__ __align__(16) float Pbuf[VOCAB * G4];
__device__ __align__(16) signed char Wqb[G4 * HID];   // int8 W_hh, row-major [gatecol][k]
__device__ float Winv[G4];                            // m/(127^2) * per-gate exp2 scale

__global__ void build_P(const float* __restrict__ emb, const float* __restrict__ W_ih,
                        const float* __restrict__ b_ih, const float* __restrict__ b_hh) {
    const int v = blockIdx.x >> 2;
    const int c = ((blockIdx.x & 3) << 8) + threadIdx.x;   // gate-col 0..1023
    __shared__ float es[EMBD];
    if (threadIdx.x < EMBD) es[threadIdx.x] = emb[v * EMBD + threadIdx.x];
    __syncthreads();
    const float* wr = W_ih + c * EMBD;
    float acc = 0.f;
    #pragma unroll 8
    for (int e = 0; e < EMBD; ++e) acc += es[e] * wr[e];
    const float ks = ((c >> 8) == 2) ? (-2.f * LOG2E) : (-LOG2E);
    // c = g*256 + w*32 + nt*16 + l15  ->  idx = v*1024 + w*128 + nt*64 + l15*4 + g
    const int g  = c >> 8;
    const int rr = c & 255;
    const int wi = rr >> 5;
    const int nt = (rr >> 4) & 1;
    const int l  = rr & 15;
    Pbuf[v * G4 + wi * 128 + nt * 64 + l * 4 + g] = (acc + b_ih[c] + b_hh[c]) * ks;
}

// per-row symmetric int8 quantization of W_hh (1024 rows x 256)
__global__ void quant_W(const float* __restrict__ W_hh) {
    const int row = blockIdx.x;
    const int k   = threadIdx.x;
    __shared__ float red[4];
    const float wv = W_hh[row * HID + k];
    float a = fabsf(wv);
    #pragma unroll
    for (int o = 32; o > 0; o >>= 1) a = fmaxf(a, __shfl_down(a, o, 64));
    if ((k & 63) == 0) red[k >> 6] = a;
    __syncthreads();
    const float m = fmaxf(fmaxf(fmaxf(red[0], red[1]), red[2]), fmaxf(red[3], 1e-30f));
    Wqb[row * HID + k] = (signed char)(int)rintf(wv * (127.f / m));
    const float ks = ((row >> 8) == 2) ? (-2.f * LOG2E) : (-LOG2E);
    if (k == 0) Winv[row] = m * (1.f / (127.f * 127.f)) * ks;
}

// r = 1/(1+2^p).  p = -x*log2e -> sigmoid(x); tanh(x) = 2*r(-2x*log2e)-1.
__device__ __forceinline__ float sig_p(float p) {
    return __builtin_amdgcn_rcpf(1.f + __builtin_amdgcn_exp2f(p));
}

// 64 WGs x 512 thr: one WG = one chain of 2 batch rows. Same per-CU matrix floor
// (256 mfma/step), but each lane owns exactly ONE gate-cell:
//   batch = quad>>1, nt = quad&1, col = ub + nt*16 + l15   (acc tile via cndmask)
// -> minimal VALU tail, 64 CUs active. (R6/R8/R10 showed MFMA/VALU phase overlap
// attempts all fail: phase-lock is structural; this config is the measured optimum.)
__global__ __launch_bounds__(512, 2) void lstm_chain(
        const int* __restrict__ x, const float* __restrict__ fc_W,
        const float* __restrict__ fc_b, float* __restrict__ out) {
    __shared__ __align__(16) signed char habuf[2][BSUB * HSB];
    __shared__ int   xch[BSUB * XCHS];
    __shared__ float hfin[BSUB * HID];

    const int tid  = threadIdx.x;
    const int w    = tid >> 6;       // wave 0..7: owns units [32w, 32w+32), all 4 gates
    const int lane = tid & 63;
    const int l15  = lane & 15;
    const int quad = lane >> 4;
    const int bbase = blockIdx.x * BSUB;
    const int ub    = w * 32;
    const int bq    = quad >> 1;              // this lane's batch row
    const int ntq   = quad & 1;               // this lane's acc tile
    const int colq  = ub + ntq * 16 + l15;    // this lane's gate-col (within gate block)

    // persistent int8 B fragments: 2 tiles x 4 gates x 4 K-chunks x 4 regs = 128 regs
    i32x4 Bf[2][4][4];
    #pragma unroll
    for (int nt = 0; nt < 2; ++nt)
        #pragma unroll
        for (int g = 0; g < 4; ++g) {
            const signed char* wr = Wqb + (size_t)(g * HID + ub + nt * 16 + l15) * HID;
            #pragma unroll
            for (int kt = 0; kt < 4; ++kt)
                Bf[nt][g][kt] = *(const i32x4*)(wr + kt * 64 + quad * 16);
        }
    float winvv[4];                           // per-gate dequant for THIS lane's col
    #pragma unroll
    for (int g = 0; g < 4; ++g) winvv[g] = Winv[g * HID + colq];

    if (tid < BSUB * HSB / 4) ((int*)habuf[0])[tid] = 0;   // h_0 = 0

    float cst = 0.f;                          // single cell state per lane
    f32x4 xga, xgb;                           // double-buffered xg (4 gates)
    const i32x4 zero4 = {0, 0, 0, 0};
    const float* pbase = Pbuf + w * 128 + ntq * 64 + l15 * 4;
    const signed char* habA = habuf[0] + (l15 >> 3) * HSB + quad * 16;
    const signed char* habB = habuf[1] + (l15 >> 3) * HSB + quad * 16;

#define GATHER(TT, XG)                                                        \
    {                                                                         \
        const int xv = xch[bq * XCHS + (TT)];                                 \
        XG = *(const f32x4*)(pbase + (size_t)xv * G4);                        \
    }

#define STEP(HAB, HN, XC, XN, PF, TT, TCUR)                                   \
    {                                                                         \
        i32x4 af[4];                                                          \
        _Pragma("unroll")                                                     \
        for (int kt = 0; kt < 4; ++kt)                                        \
            af[kt] = *(const i32x4*)((HAB) + kt * 64);                        \
        if (PF) GATHER((TT), XN);                                             \
        i32x4 a0[4], a1[4];                                                   \
        _Pragma("unroll")                                                     \
        for (int g = 0; g < 4; ++g)                                           \
            a0[g] = __builtin_amdgcn_mfma_i32_16x16x64_i8(af[0], Bf[0][g][0], zero4, 0, 0, 0); \
        _Pragma("unroll")                                                     \
        for (int kt = 1; kt < 4; ++kt)                                        \
            _Pragma("unroll")                                                 \
            for (int g = 0; g < 4; ++g)                                       \
                a0[g] = __builtin_amdgcn_mfma_i32_16x16x64_i8(af[kt], Bf[0][g][kt], a0[g], 0, 0, 0); \
        _Pragma("unroll")                                                     \
        for (int g = 0; g < 4; ++g)                                           \
            a1[g] = __builtin_amdgcn_mfma_i32_16x16x64_i8(af[0], Bf[1][g][0], zero4, 0, 0, 0); \
        _Pragma("unroll")                                                     \
        for (int kt = 1; kt < 4; ++kt)                                        \
            _Pragma("unroll")                                                 \
            for (int g = 0; g < 4; ++g)                                       \
                a1[g] = __builtin_amdgcn_mfma_i32_16x16x64_i8(af[kt], Bf[1][g][kt], a1[g], 0, 0, 0); \
        /* ONE gate-cell per lane: tile select via cndmask */                 \
        const int gi_ = ntq ? a1[0][0] : a0[0][0];                            \
        const int gf_ = ntq ? a1[1][0] : a0[1][0];                            \
        const int gg_ = ntq ? a1[2][0] : a0[2][0];                            \
        const int go_ = ntq ? a1[3][0] : a0[3][0];                            \
        const float is = sig_p(fmaf((float)gi_, winvv[0], XC[0]));            \
        const float fs = sig_p(fmaf((float)gf_, winvv[1], XC[1]));            \
        const float gt = fmaf(2.f, sig_p(fmaf((float)gg_, winvv[2], XC[2])), -1.f); \
        const float os = sig_p(fmaf((float)go_, winvv[3], XC[3]));            \
        const float c  = fmaf(fs, cst, is * gt);                              \
        cst = c;                                                              \
        const float hq = fmaf(254.f, sig_p(c * (-2.f * LOG2E)), -127.f) * os; \
        (HN)[bq * HSB + colq] = (signed char)(int)rintf(hq);                  \
        if ((TCUR) == T_LEN - 1) hfin[bq * HID + colq] = hq * (1.f / 127.f);  \
        __syncthreads();                                                      \
    }

    #pragma unroll 1
    for (int ch = 0; ch < T_LEN / CHK; ++ch) {
        // refill x chunk (prev step's end-barrier protects old readers)
        if (tid < BSUB * CHK)
            xch[(tid >> 6) * XCHS + (tid & 63)] =
                x[(bbase + (tid >> 6)) * T_LEN + ch * CHK + (tid & 63)];
        __syncthreads();
        GATHER(0, xga);
        const int tb = ch * CHK;
        #pragma unroll 1
        for (int tt = 0; tt < CHK; tt += 2) {
            STEP(habA, habuf[1], xga, xgb, 1, tt + 1, tb + tt);
            STEP(habB, habuf[0], xgb, xga, (tt < CHK - 2), tt + 2, tb + tt + 1);
        }
    }
#undef STEP
#undef GATHER

    // FC epilogue: logits[b,o] = hT[b,:] . fc_W[o,:] + fc_b[o]
    if (tid < BSUB * OUTC) {
        const int b = tid >> 1, o = tid & 1;
        float s = fc_b[o];
        #pragma unroll 8
        for (int j = 0; j < HID; ++j) s += hfin[b * HID + j] * fc_W[o * HID + j];
        out[(bbase + b) * OUTC + o] = s;
    }
}

extern "C" void kernel_launch(void* const* d_in, const int* in_sizes, int n_in,
                              void* d_out, int out_size, void* d_ws, size_t ws_size,
                              hipStream_t stream) {
    const int*   x    = (const int*)  d_in[0];
    const float* emb  = (const float*)d_in[1];
    const float* W_ih = (const float*)d_in[2];
    const float* W_hh = (const float*)d_in[3];
    const float* b_ih = (const float*)d_in[4];
    const float* b_hh = (const float*)d_in[5];
    const float* fc_W = (const float*)d_in[6];
    const float* fc_b = (const float*)d_in[7];
    float* out = (float*)d_out;
    (void)d_ws; (void)ws_size;

    build_P<<<dim3(VOCAB * 4), dim3(256), 0, stream>>>(emb, W_ih, b_ih, b_hh);
    quant_W<<<dim3(G4), dim3(HID), 0, stream>>>(W_hh);
    lstm_chain<<<dim3(NWG), dim3(512), 0, stream>>>(x, fc_W, fc_b, out);
}